// Round 1
// baseline (136.729 us; speedup 1.0000x reference)
//
#include <hip/hip_runtime.h>

// EPN layer: B=8, N=256, F=32, E_DIM=8, HID=32, IN_DIM=74, T=3
// Inputs (dict order): h[8,256,32], e[8,256,256,8], q[8,256,1], mask[8,256],
//   W1[3,74,32], b1[3,32], W2[3,32,32], b2[3,32], W3[3,32,1], b3[3,1]
// Output: q final [8,256,1] fp32.

#define F4(p) (*(const float4*)(p))

// P[node,k] = b1[k] + q*W1[32,k] + sum_f h[f]*W1[f,k]        (inp_i side)
// Q[node,k] =         q*W1[65,k] + sum_f h[f]*W1[33+f,k]     (inp_j side)
__global__ __launch_bounds__(256) void epn_pre(
    const float* __restrict__ h, const float* __restrict__ q,
    const float* __restrict__ W1, const float* __restrict__ b1,
    float* __restrict__ P, float* __restrict__ Q)
{
    int gid  = blockIdx.x * 256 + threadIdx.x;   // node*32 + k
    int node = gid >> 5;
    int k    = gid & 31;
    const float* hn = h + node * 32;
    float qv = q[node];
    float p  = b1[k] + qv * W1[32*32 + k];
    float qq =         qv * W1[65*32 + k];
    #pragma unroll
    for (int f = 0; f < 32; ++f) {
        float hv = hn[f];
        p  += hv * W1[f*32 + k];
        qq += hv * W1[(33+f)*32 + k];
    }
    P[gid] = p;
    Q[gid] = qq;
}

#define FMA4(acc, base, s, w) \
    acc[(base)+0] += (s)*(w).x; acc[(base)+1] += (s)*(w).y; \
    acc[(base)+2] += (s)*(w).z; acc[(base)+3] += (s)*(w).w;

// One block per (b,i) = blockIdx.x; one thread per j.
__global__ __launch_bounds__(256) void epn_main(
    const float* __restrict__ e,    // [8,256,256,8]
    const float* __restrict__ mask, // [8,256]
    const float* __restrict__ P,    // [2048,32]
    const float* __restrict__ Qm,   // [2048,32]
    const float* __restrict__ W1e,  // 8x32  (W1 rows 66..73 for this t)
    const float* __restrict__ W2,   // 32x32
    const float* __restrict__ b2,   // 32
    const float* __restrict__ W3,   // 32
    const float* __restrict__ q_src,
    float* __restrict__ q_dst)
{
    __shared__ float sRed[4];

    const int bi  = blockIdx.x;       // b*256 + i
    const int b   = bi >> 8;
    const int tid = threadIdx.x;
    const int j   = tid;

    // ---- per-pair e vector (coalesced: 32B/thread contiguous) ----
    const float* ejp = e + ((size_t)bi * 256 + j) * 8;
    float4 e0 = F4(ejp);
    float4 e1 = F4(ejp + 4);
    float er[8] = {e0.x, e0.y, e0.z, e0.w, e1.x, e1.y, e1.z, e1.w};

    // is_near = (clip(max_d e, 1e-8, 1e5) != 1e-8)
    float mx = er[0];
    #pragma unroll
    for (int d = 1; d < 8; ++d) mx = fmaxf(mx, er[d]);
    float clipped = fminf(fmaxf(mx, 1e-8f), 1e5f);
    float near = (clipped != 1e-8f) ? 1.0f : 0.0f;
    float em = mask[bi] * mask[b * 256 + j];

    // ---- E term: e @ W1e  (shared between both directions); W1e uniform -> s_load
    float E[32];
    #pragma unroll
    for (int k = 0; k < 32; ++k) E[k] = 0.f;
    #pragma unroll
    for (int d = 0; d < 8; ++d) {
        float ev = er[d];
        #pragma unroll
        for (int kc = 0; kc < 8; ++kc) {
            float4 w = F4(W1e + d*32 + kc*4);
            FMA4(E, kc*4, ev, w)
        }
    }

    // ---- layer 1: x1a = relu(P[i]+Q[j]+E), x1b = relu(P[j]+Q[i]+E)
    const float* Pi = P  + (size_t)bi * 32;           // uniform
    const float* Qi = Qm + (size_t)bi * 32;           // uniform
    const float* Pj = P  + ((size_t)(b*256) + j) * 32;
    const float* Qj = Qm + ((size_t)(b*256) + j) * 32;
    float x1a[32], x1b[32];
    #pragma unroll
    for (int kc = 0; kc < 8; ++kc) {
        float4 pi = F4(Pi + kc*4);
        float4 qi = F4(Qi + kc*4);
        float4 pj = F4(Pj + kc*4);
        float4 qj = F4(Qj + kc*4);
        x1a[kc*4+0] = fmaxf(pi.x + qj.x + E[kc*4+0], 0.f);
        x1a[kc*4+1] = fmaxf(pi.y + qj.y + E[kc*4+1], 0.f);
        x1a[kc*4+2] = fmaxf(pi.z + qj.z + E[kc*4+2], 0.f);
        x1a[kc*4+3] = fmaxf(pi.w + qj.w + E[kc*4+3], 0.f);
        x1b[kc*4+0] = fmaxf(pj.x + qi.x + E[kc*4+0], 0.f);
        x1b[kc*4+1] = fmaxf(pj.y + qi.y + E[kc*4+1], 0.f);
        x1b[kc*4+2] = fmaxf(pj.z + qi.z + E[kc*4+2], 0.f);
        x1b[kc*4+3] = fmaxf(pj.w + qi.w + E[kc*4+3], 0.f);
    }

    // ---- layer 2: y = b2 + x1 @ W2  (W2 uniform; each row shared by both dirs)
    float ya[32], yb[32];
    #pragma unroll
    for (int kc = 0; kc < 8; ++kc) {
        float4 bb = F4(b2 + kc*4);
        ya[kc*4+0] = bb.x; ya[kc*4+1] = bb.y; ya[kc*4+2] = bb.z; ya[kc*4+3] = bb.w;
        yb[kc*4+0] = bb.x; yb[kc*4+1] = bb.y; yb[kc*4+2] = bb.z; yb[kc*4+3] = bb.w;
    }
    #pragma unroll
    for (int c = 0; c < 32; ++c) {
        float a  = x1a[c];
        float bv = x1b[c];
        #pragma unroll
        for (int kc = 0; kc < 8; ++kc) {
            float4 w = F4(W2 + c*32 + kc*4);
            FMA4(ya, kc*4, a,  w)
            FMA4(yb, kc*4, bv, w)
        }
    }

    // ---- layer 3: s = relu(y) @ W3   (b3 cancels in the antisymmetric diff)
    float sa = 0.f, sb = 0.f;
    #pragma unroll
    for (int kc = 0; kc < 8; ++kc) {
        float4 w = F4(W3 + kc*4);
        sa += fmaxf(ya[kc*4+0], 0.f)*w.x + fmaxf(ya[kc*4+1], 0.f)*w.y
            + fmaxf(ya[kc*4+2], 0.f)*w.z + fmaxf(ya[kc*4+3], 0.f)*w.w;
        sb += fmaxf(yb[kc*4+0], 0.f)*w.x + fmaxf(yb[kc*4+1], 0.f)*w.y
            + fmaxf(yb[kc*4+2], 0.f)*w.z + fmaxf(yb[kc*4+3], 0.f)*w.w;
    }

    float contrib = 0.5f * (sa - sb) * em * near;

    // ---- block reduction over j ----
    #pragma unroll
    for (int off = 32; off > 0; off >>= 1)
        contrib += __shfl_down(contrib, off);
    if ((tid & 63) == 0) sRed[tid >> 6] = contrib;
    __syncthreads();
    if (tid == 0) {
        float tot = sRed[0] + sRed[1] + sRed[2] + sRed[3];
        q_dst[bi] = q_src[bi] + tot;
    }
}

extern "C" void kernel_launch(void* const* d_in, const int* in_sizes, int n_in,
                              void* d_out, int out_size, void* d_ws, size_t ws_size,
                              hipStream_t stream) {
    (void)in_sizes; (void)n_in; (void)out_size; (void)ws_size;
    const float* h    = (const float*)d_in[0];
    const float* e    = (const float*)d_in[1];
    const float* q    = (const float*)d_in[2];
    const float* mask = (const float*)d_in[3];
    const float* W1   = (const float*)d_in[4];
    const float* b1   = (const float*)d_in[5];
    const float* W2   = (const float*)d_in[6];
    const float* b2   = (const float*)d_in[7];
    const float* W3   = (const float*)d_in[8];

    float* wsf = (float*)d_ws;
    float* P  = wsf;                 // 2048*32
    float* Qm = P + 2048*32;         // 2048*32
    float* qA = Qm + 2048*32;        // 2048
    float* qB = qA + 2048;           // 2048

    const float* qcur = q;
    for (int t = 0; t < 3; ++t) {
        epn_pre<<<256, 256, 0, stream>>>(h, qcur, W1 + t*74*32, b1 + t*32, P, Qm);
        float* qdst = (t == 2) ? (float*)d_out : (t == 0 ? qA : qB);
        epn_main<<<2048, 256, 0, stream>>>(e, mask, P, Qm,
                                           W1 + t*74*32 + 66*32,
                                           W2 + t*32*32, b2 + t*32, W3 + t*32,
                                           qcur, qdst);
        qcur = qdst;
    }
}

// Round 2
// 106.769 us; speedup vs baseline: 1.2806x; 1.2806x over previous
//
#include <hip/hip_runtime.h>
#include <hip/hip_bf16.h>

// EPN layer: B=8, N=256, F=32, E_DIM=8, HID=32, IN_DIM=74, T=3
// q_out = q + sum_j 0.5*(mlp(i,j) - mlp(j,i)) * mask_i*mask_j * is_near
// Decomposition: x1a = relu(P_i + Q_j + E_ij), x1b = relu(P_j + Q_i + E_ij)
//   P = [h,q]@W1[0:33] + b1 (inp_i rows), Q = [h,q]@W1[33:66] (inp_j rows),
//   E = e@W1[66:74]. b3 cancels in the antisymmetric difference.
// Layer 2 (x1@W2) runs on MFMA bf16; everything else fp32 VALU.

#define F4(p) (*(const float4*)(p))

typedef __attribute__((ext_vector_type(8))) short short8;
typedef __attribute__((ext_vector_type(4))) float f32x4;

union U4S8 { uint4 u; short8 s; };

__device__ __forceinline__ unsigned pkbf2(float lo, float hi) {
    unsigned a = __bfloat16_as_ushort(__float2bfloat16(lo));
    unsigned b = __bfloat16_as_ushort(__float2bfloat16(hi));
    return a | (b << 16);
}

// P/Q per node + W2 transpose-pack to bf16 (W2T[n][k] pairs, u32 = {k even lo, k odd hi})
__global__ __launch_bounds__(256) void epn_pre(
    const float* __restrict__ h, const float* __restrict__ q,
    const float* __restrict__ W1, const float* __restrict__ b1,
    const float* __restrict__ W2,
    float* __restrict__ P, float* __restrict__ Q, unsigned* __restrict__ W2T)
{
    int gid  = blockIdx.x * 256 + threadIdx.x;   // node*32 + k
    if (gid < 512) {
        int n = gid >> 4, kp = gid & 15;
        W2T[gid] = pkbf2(W2[(2*kp)*32 + n], W2[(2*kp+1)*32 + n]);
    }
    int node = gid >> 5;
    int k    = gid & 31;
    const float* hn = h + node * 32;
    float qv = q[node];
    float p  = b1[k] + qv * W1[32*32 + k];
    float qq =         qv * W1[65*32 + k];
    #pragma unroll
    for (int f = 0; f < 32; ++f) {
        float hv = hn[f];
        p  += hv * W1[f*32 + k];
        qq += hv * W1[(33+f)*32 + k];
    }
    P[gid] = p;
    Q[gid] = qq;
}

// One block per (b,i); thread j does phase-1 (E, x1a, x1b -> LDS bf16);
// phase-2: 16 MFMAs/wave for layer 2, epilogue folds b2/relu/W3/mn/sign/sum.
__global__ __launch_bounds__(256) void epn_main(
    const float* __restrict__ e,    // [8,256,256,8]
    const float* __restrict__ mask, // [8,256]
    const float* __restrict__ P,    // [2048,32]
    const float* __restrict__ Qm,   // [2048,32]
    const float* __restrict__ W1e,  // 8x32 fp32 (W1 rows 66..73)
    const unsigned* __restrict__ W2T, // [32][16] u32 (bf16-pair W2^T)
    const float* __restrict__ b2,   // 32
    const float* __restrict__ W3,   // 32
    const float* __restrict__ q_src,
    float* __restrict__ q_dst)
{
    // slice-major x1 store: sx[slice][row], row = dir*256 + j, 16B per entry.
    __shared__ uint4 sx[4][512];     // 32 KiB
    __shared__ float mnL[256];
    __shared__ float red[4];

    const int bi  = blockIdx.x;      // b*256 + i
    const int b   = bi >> 8;
    const int tid = threadIdx.x;
    const int j   = tid;

    // ---------- phase 1: per-pair scalar work ----------
    const float* ejp = e + ((size_t)bi * 256 + j) * 8;
    float4 e0 = F4(ejp);
    float4 e1 = F4(ejp + 4);
    float er[8] = {e0.x, e0.y, e0.z, e0.w, e1.x, e1.y, e1.z, e1.w};

    float mx = er[0];
    #pragma unroll
    for (int d = 1; d < 8; ++d) mx = fmaxf(mx, er[d]);
    float clipped = fminf(fmaxf(mx, 1e-8f), 1e5f);
    float nearf = (clipped != 1e-8f) ? 1.0f : 0.0f;
    float mn = 0.5f * mask[bi] * mask[b * 256 + j] * nearf;
    mnL[j] = mn;

    // E = e @ W1e  (shared by both directions)
    float E[32];
    #pragma unroll
    for (int k = 0; k < 32; ++k) E[k] = 0.f;
    #pragma unroll
    for (int d = 0; d < 8; ++d) {
        float ev = er[d];
        #pragma unroll
        for (int kc = 0; kc < 8; ++kc) {
            float4 w = F4(W1e + d*32 + kc*4);
            E[kc*4+0] += ev * w.x; E[kc*4+1] += ev * w.y;
            E[kc*4+2] += ev * w.z; E[kc*4+3] += ev * w.w;
        }
    }

    const float* Pi = P  + (size_t)bi * 32;           // uniform -> s_load
    const float* Qi = Qm + (size_t)bi * 32;           // uniform
    const float* Pj = P  + ((size_t)(b*256) + j) * 32;
    const float* Qj = Qm + ((size_t)(b*256) + j) * 32;

    #pragma unroll
    for (int s = 0; s < 4; ++s) {
        float xa[8], xb[8];
        #pragma unroll
        for (int c2 = 0; c2 < 2; ++c2) {
            float4 pi = F4(Pi + s*8 + c2*4);
            float4 qi = F4(Qi + s*8 + c2*4);
            float4 pj = F4(Pj + s*8 + c2*4);
            float4 qj = F4(Qj + s*8 + c2*4);
            int o = c2*4, ke = s*8 + c2*4;
            xa[o+0] = fmaxf(pi.x + qj.x + E[ke+0], 0.f);
            xa[o+1] = fmaxf(pi.y + qj.y + E[ke+1], 0.f);
            xa[o+2] = fmaxf(pi.z + qj.z + E[ke+2], 0.f);
            xa[o+3] = fmaxf(pi.w + qj.w + E[ke+3], 0.f);
            xb[o+0] = fmaxf(pj.x + qi.x + E[ke+0], 0.f);
            xb[o+1] = fmaxf(pj.y + qi.y + E[ke+1], 0.f);
            xb[o+2] = fmaxf(pj.z + qi.z + E[ke+2], 0.f);
            xb[o+3] = fmaxf(pj.w + qi.w + E[ke+3], 0.f);
        }
        sx[s][j]       = make_uint4(pkbf2(xa[0],xa[1]), pkbf2(xa[2],xa[3]),
                                    pkbf2(xa[4],xa[5]), pkbf2(xa[6],xa[7]));
        sx[s][256 + j] = make_uint4(pkbf2(xb[0],xb[1]), pkbf2(xb[2],xb[3]),
                                    pkbf2(xb[4],xb[5]), pkbf2(xb[6],xb[7]));
    }
    __syncthreads();

    // ---------- phase 2: layer-2 MFMA + fused epilogue ----------
    const int lane = tid & 63, w = tid >> 6;
    const int l15  = lane & 15, sl = lane >> 4;

    float b2v0 = b2[l15],      b2v1 = b2[l15 + 16];
    float w3v0 = W3[l15],      w3v1 = W3[l15 + 16];
    const uint4* bp = (const uint4*)W2T;
    U4S8 bu0, bu1;
    bu0.u = bp[l15 * 4 + sl];          // cols 0..15,  k-slice sl
    bu1.u = bp[(l15 + 16) * 4 + sl];   // cols 16..31

    float tot = 0.f;
    #pragma unroll
    for (int rg = 0; rg < 4; ++rg) {
        int jb = w * 64 + rg * 16;
        float m0 = mnL[jb + sl*4 + 0];
        float m1 = mnL[jb + sl*4 + 1];
        float m2 = mnL[jb + sl*4 + 2];
        float m3 = mnL[jb + sl*4 + 3];
        #pragma unroll
        for (int dir = 0; dir < 2; ++dir) {
            U4S8 au; au.u = sx[sl][dir*256 + jb + l15];   // A: row=l15, k-slice=sl
            f32x4 z = {0.f, 0.f, 0.f, 0.f};
            f32x4 d0 = __builtin_amdgcn_mfma_f32_16x16x32_bf16(au.s, bu0.s, z, 0, 0, 0);
            f32x4 d1 = __builtin_amdgcn_mfma_f32_16x16x32_bf16(au.s, bu1.s, z, 0, 0, 0);
            // C layout: col=l15(+16), row=jb+sl*4+r
            float p0 = fmaxf(d0[0]+b2v0,0.f)*w3v0 + fmaxf(d1[0]+b2v1,0.f)*w3v1;
            float p1 = fmaxf(d0[1]+b2v0,0.f)*w3v0 + fmaxf(d1[1]+b2v1,0.f)*w3v1;
            float p2 = fmaxf(d0[2]+b2v0,0.f)*w3v0 + fmaxf(d1[2]+b2v1,0.f)*w3v1;
            float p3 = fmaxf(d0[3]+b2v0,0.f)*w3v0 + fmaxf(d1[3]+b2v1,0.f)*w3v1;
            float ss = m0*p0 + m1*p1 + m2*p2 + m3*p3;
            tot += dir ? -ss : ss;
        }
    }
    #pragma unroll
    for (int off = 32; off > 0; off >>= 1) tot += __shfl_down(tot, off);
    if (lane == 0) red[w] = tot;
    __syncthreads();
    if (tid == 0) q_dst[bi] = q_src[bi] + red[0] + red[1] + red[2] + red[3];
}

extern "C" void kernel_launch(void* const* d_in, const int* in_sizes, int n_in,
                              void* d_out, int out_size, void* d_ws, size_t ws_size,
                              hipStream_t stream) {
    (void)in_sizes; (void)n_in; (void)out_size; (void)ws_size;
    const float* h    = (const float*)d_in[0];
    const float* e    = (const float*)d_in[1];
    const float* q    = (const float*)d_in[2];
    const float* mask = (const float*)d_in[3];
    const float* W1   = (const float*)d_in[4];
    const float* b1   = (const float*)d_in[5];
    const float* W2   = (const float*)d_in[6];
    const float* b2   = (const float*)d_in[7];
    const float* W3   = (const float*)d_in[8];

    float* wsf = (float*)d_ws;
    float* P   = wsf;                 // 2048*32
    float* Qm  = P + 2048*32;         // 2048*32
    float* qA  = Qm + 2048*32;        // 2048
    float* qB  = qA + 2048;           // 2048
    unsigned* W2T = (unsigned*)(qB + 2048);  // 512 u32, 16B-aligned

    const float* qcur = q;
    for (int t = 0; t < 3; ++t) {
        epn_pre<<<256, 256, 0, stream>>>(h, qcur, W1 + t*74*32, b1 + t*32,
                                         W2 + t*32*32, P, Qm, W2T);
        float* qdst = (t == 2) ? (float*)d_out : (t == 0 ? qA : qB);
        epn_main<<<2048, 256, 0, stream>>>(e, mask, P, Qm,
                                           W1 + t*74*32 + 66*32, W2T,
                                           b2 + t*32, W3 + t*32,
                                           qcur, qdst);
        qcur = qdst;
    }
}

// Round 3
// 71.025 us; speedup vs baseline: 1.9251x; 1.5033x over previous
//
#include <hip/hip_runtime.h>
#include <hip/hip_bf16.h>

// EPN layer: B=8, N=256, F=32, E_DIM=8, HID=32, IN_DIM=74, T=3
// Decomposition per t:
//   P[n] = [h_n,q_n]@W1[0:33] + b1   (fp32 + bf16 copies)
//   Q[n] = [h_n,q_n]@W1[33:66]      (fp32 + bf16 copies)
//   elec_ij = mlp_tail( relu(P_i + Q_j + e_ij@W1e) )   (dir 0)
//   elec_ji = mlp_tail( relu(Q_i + P_j + e_ij@W1e) )   (dir 1)
//   q_next = q + 0.5*(S0 - S1),  S_dir[i] = sum_j mn_ij * elec
// Layer 1: MFMA (A = e rows bf16, K=8 valid of 32; C = splat(P_i/Q_i) fp32),
//   + bf16 J-row add + relu in epilogue. Layer 2: MFMA (round-2 validated
//   W2T fragments). Layer 3 + mask + reduction fused in epilogue.
// One block per (b, i, dir): grid 4096, 2x wave parallelism vs round 2.

typedef __attribute__((ext_vector_type(8))) short short8;
typedef __attribute__((ext_vector_type(4))) float f32x4;
union U4S8 { uint4 u; short8 s; };

__device__ __forceinline__ unsigned pkbf2(float lo, float hi) {
    unsigned a = __bfloat16_as_ushort(__float2bfloat16(lo));
    unsigned b = __bfloat16_as_ushort(__float2bfloat16(hi));
    return a | (b << 16);
}
__device__ __forceinline__ unsigned short f2bf(float x) {
    return __bfloat16_as_ushort(__float2bfloat16(x));
}
__device__ __forceinline__ float bf2f(unsigned short u) {
    return __uint_as_float(((unsigned)u) << 16);
}

// P/Q (fp32 + bf16), q_t materialization, W2T + W1eF fragment prepack.
__global__ __launch_bounds__(256) void epn_pre(
    const float* __restrict__ h, const float* __restrict__ qprev,
    const float* __restrict__ S, int use_parts,
    const float* __restrict__ W1, const float* __restrict__ b1,
    const float* __restrict__ W2,
    float* __restrict__ P, float* __restrict__ Q,
    unsigned short* __restrict__ Pbf, unsigned short* __restrict__ Qbf,
    unsigned* __restrict__ W2T, unsigned* __restrict__ W1eF,
    float* __restrict__ qt)
{
    int gid = blockIdx.x * 256 + threadIdx.x;
    if (gid < 512) {
        // W2^T bf16-pair pack (validated in round 2)
        int n = gid >> 4, kp = gid & 15;
        W2T[gid] = pkbf2(W2[(2*kp)*32 + n], W2[(2*kp+1)*32 + n]);
    } else if (gid < 1024) {
        // Layer-1 B fragments: lane L=(l15,sl), ct in {0,1}, uint u holds
        // k = sl*8+2u, sl*8+2u+1 of B[k][c]=W1e[k][ct*16+l15] (zero for k>=8)
        int g2 = gid - 512;
        int L = g2 >> 3, rest = g2 & 7;
        int ct = rest >> 2, u = rest & 3;
        int l15 = L & 15, sl = L >> 4;
        float lo = 0.f, hi = 0.f;
        if (sl == 0) {
            lo = W1[(66 + 2*u)*32 + ct*16 + l15];
            hi = W1[(66 + 2*u + 1)*32 + ct*16 + l15];
        }
        W1eF[g2] = pkbf2(lo, hi);
    }
    int node = gid >> 5;
    int k    = gid & 31;
    float qv = qprev[node];
    if (use_parts) qv += 0.5f * (S[node] - S[2048 + node]);
    if (k == 0) qt[node] = qv;
    const float* hn = h + node * 32;
    float p  = b1[k] + qv * W1[32*32 + k];
    float qq =         qv * W1[65*32 + k];
    #pragma unroll
    for (int f = 0; f < 32; ++f) {
        float hv = hn[f];
        p  += hv * W1[f*32 + k];
        qq += hv * W1[(33+f)*32 + k];
    }
    P[gid] = p;   Q[gid] = qq;
    Pbf[gid] = f2bf(p);
    Qbf[gid] = f2bf(qq);
}

// One block per (b,i,dir). Writes Sout[dir*2048 + bi] = sum_j mn * elec.
__global__ __launch_bounds__(256, 4) void epn_main(
    const float* __restrict__ e, const float* __restrict__ mask,
    const float* __restrict__ P, const float* __restrict__ Q,
    const uint4* __restrict__ Pbf4, const uint4* __restrict__ Qbf4,
    const uint4* __restrict__ W1eF4, const unsigned* __restrict__ W2T,
    const float* __restrict__ b2, const float* __restrict__ W3,
    float* __restrict__ Sout)
{
    __shared__ uint4 eL[257];                    // e rows bf16; row 256 = zeros
    __shared__ uint4 Jrow4[256*4];               // J-side bf16 rows [256][16 uints]
    __shared__ unsigned short sxu[4][256][8];    // x1, slice-major (round-2 layout)
    __shared__ float mnL[256];
    __shared__ float red[4];

    const int bid  = blockIdx.x;
    const int dir  = bid & 1;
    const int bi   = bid >> 1;        // b*256 + i
    const int b    = bi >> 8;
    const int tid  = threadIdx.x;
    const int j    = tid;
    const int lane = tid & 63, w = tid >> 6;
    const int l15  = lane & 15, sl = lane >> 4;

    // ---------- staging ----------
    const float* ejp = e + ((size_t)bi * 256 + j) * 8;
    float4 e0 = *(const float4*)ejp;
    float4 e1 = *(const float4*)(ejp + 4);
    float mx = fmaxf(fmaxf(fmaxf(e0.x,e0.y),fmaxf(e0.z,e0.w)),
                     fmaxf(fmaxf(e1.x,e1.y),fmaxf(e1.z,e1.w)));
    float clipped = fminf(fmaxf(mx, 1e-8f), 1e5f);
    float nearf = (clipped != 1e-8f) ? 1.0f : 0.0f;
    mnL[j] = mask[bi] * mask[b*256 + j] * nearf;   // 0.5 applied at combine
    eL[j] = make_uint4(pkbf2(e0.x,e0.y), pkbf2(e0.z,e0.w),
                       pkbf2(e1.x,e1.y), pkbf2(e1.z,e1.w));
    if (j == 0) eL[256] = make_uint4(0u,0u,0u,0u);
    // J-side rows (dir0: Q_j, dir1: P_j), rotated assignment for bank spread
    const uint4* Jsrc = dir ? Pbf4 : Qbf4;
    {
        int rbase = (j >> 2) * 4, cch = j & 3;
        #pragma unroll
        for (int r = 0; r < 4; ++r) {
            int row = rbase + r;
            Jrow4[row*4 + cch] = Jsrc[(b*256 + row)*4 + cch];
        }
    }
    __syncthreads();

    // ---------- phase A: layer-1 MFMA ----------
    const float* Csrc = dir ? Q : P;               // dir0: Pi, dir1: Qi
    float cv0 = Csrc[bi*32 + l15];
    float cv1 = Csrc[bi*32 + 16 + l15];
    f32x4 c0s = {cv0, cv0, cv0, cv0};
    f32x4 c1s = {cv1, cv1, cv1, cv1};
    U4S8 bw0, bw1;
    bw0.u = W1eF4[lane*2 + 0];
    bw1.u = W1eF4[lane*2 + 1];
    U4S8 af[4];
    #pragma unroll
    for (int rt = 0; rt < 4; ++rt)
        af[rt].u = eL[(sl == 0) ? (w*64 + rt*16 + l15) : 256];
    f32x4 d[4][2];
    #pragma unroll
    for (int rt = 0; rt < 4; ++rt) {
        d[rt][0] = __builtin_amdgcn_mfma_f32_16x16x32_bf16(af[rt].s, bw0.s, c0s, 0,0,0);
        d[rt][1] = __builtin_amdgcn_mfma_f32_16x16x32_bf16(af[rt].s, bw1.s, c1s, 0,0,0);
    }
    // epilogue-1: + J-row, relu, bf16, transpose-store to slice-major sx
    const unsigned short* jr = (const unsigned short*)Jrow4;
    #pragma unroll
    for (int rt = 0; rt < 4; ++rt) {
        #pragma unroll
        for (int ct = 0; ct < 2; ++ct) {
            int c = ct*16 + l15;
            #pragma unroll
            for (int r = 0; r < 4; ++r) {
                int p = w*64 + rt*16 + sl*4 + r;     // C layout: row=sl*4+r
                float x = d[rt][ct][r] + bf2f(jr[p*32 + c]);
                sxu[c >> 3][p][c & 7] = f2bf(fmaxf(x, 0.f));
            }
        }
    }
    __syncthreads();

    // ---------- phase B: layer-2 MFMA + fused epilogue (round-2 validated) ----------
    float b2v0 = b2[l15], b2v1 = b2[l15 + 16];
    float w3v0 = W3[l15], w3v1 = W3[l15 + 16];
    const uint4* bp = (const uint4*)W2T;
    U4S8 bu0, bu1;
    bu0.u = bp[l15*4 + sl];
    bu1.u = bp[(l15 + 16)*4 + sl];
    U4S8 aus[4];
    #pragma unroll
    for (int rg = 0; rg < 4; ++rg)
        aus[rg].u = *(const uint4*)&sxu[sl][w*64 + rg*16 + l15][0];
    float tot = 0.f;
    f32x4 z = {0.f, 0.f, 0.f, 0.f};
    #pragma unroll
    for (int rg = 0; rg < 4; ++rg) {
        int jb = w*64 + rg*16;
        f32x4 d0 = __builtin_amdgcn_mfma_f32_16x16x32_bf16(aus[rg].s, bu0.s, z, 0,0,0);
        f32x4 d1 = __builtin_amdgcn_mfma_f32_16x16x32_bf16(aus[rg].s, bu1.s, z, 0,0,0);
        float m0 = mnL[jb + sl*4 + 0];
        float m1 = mnL[jb + sl*4 + 1];
        float m2 = mnL[jb + sl*4 + 2];
        float m3 = mnL[jb + sl*4 + 3];
        float p0 = fmaxf(d0[0]+b2v0,0.f)*w3v0 + fmaxf(d1[0]+b2v1,0.f)*w3v1;
        float p1 = fmaxf(d0[1]+b2v0,0.f)*w3v0 + fmaxf(d1[1]+b2v1,0.f)*w3v1;
        float p2 = fmaxf(d0[2]+b2v0,0.f)*w3v0 + fmaxf(d1[2]+b2v1,0.f)*w3v1;
        float p3 = fmaxf(d0[3]+b2v0,0.f)*w3v0 + fmaxf(d1[3]+b2v1,0.f)*w3v1;
        tot += m0*p0 + m1*p1 + m2*p2 + m3*p3;
    }
    #pragma unroll
    for (int off = 32; off > 0; off >>= 1) tot += __shfl_down(tot, off);
    if (lane == 0) red[w] = tot;
    __syncthreads();
    if (tid == 0) Sout[dir*2048 + bi] = red[0] + red[1] + red[2] + red[3];
}

__global__ __launch_bounds__(256) void epn_fin(
    const float* __restrict__ qt, const float* __restrict__ S,
    float* __restrict__ out)
{
    int n = blockIdx.x * 256 + threadIdx.x;
    out[n] = qt[n] + 0.5f * (S[n] - S[2048 + n]);
}

extern "C" void kernel_launch(void* const* d_in, const int* in_sizes, int n_in,
                              void* d_out, int out_size, void* d_ws, size_t ws_size,
                              hipStream_t stream) {
    (void)in_sizes; (void)n_in; (void)out_size; (void)ws_size;
    const float* h    = (const float*)d_in[0];
    const float* e    = (const float*)d_in[1];
    const float* q    = (const float*)d_in[2];
    const float* mask = (const float*)d_in[3];
    const float* W1   = (const float*)d_in[4];
    const float* b1   = (const float*)d_in[5];
    const float* W2   = (const float*)d_in[6];
    const float* b2   = (const float*)d_in[7];
    const float* W3   = (const float*)d_in[8];

    float* wsf = (float*)d_ws;
    float* P   = wsf;                                   // [2048][32]
    float* Qm  = wsf + 65536;                           // [2048][32]
    unsigned short* Pbf = (unsigned short*)(wsf + 131072);  // 128KB
    unsigned short* Qbf = (unsigned short*)(wsf + 163840);  // 128KB
    float* qtA = wsf + 196608;                          // 2048
    float* qtB = wsf + 198656;                          // 2048
    float* S   = wsf + 200704;                          // [2][2048]
    unsigned* W2T  = (unsigned*)(wsf + 204800);         // 512
    unsigned* W1eF = (unsigned*)(wsf + 205312);         // 512

    for (int t = 0; t < 3; ++t) {
        const float* qsrc = (t == 0) ? q : (t == 1 ? qtA : qtB);
        float* qt_out     = (t == 1) ? qtB : qtA;
        epn_pre<<<256, 256, 0, stream>>>(h, qsrc, S, (t > 0) ? 1 : 0,
                                         W1 + t*74*32, b1 + t*32, W2 + t*32*32,
                                         P, Qm, Pbf, Qbf, W2T, W1eF, qt_out);
        epn_main<<<4096, 256, 0, stream>>>(e, mask, P, Qm,
                                           (const uint4*)Pbf, (const uint4*)Qbf,
                                           (const uint4*)W1eF, W2T,
                                           b2 + t*32, W3 + t*32, S);
    }
    epn_fin<<<8, 256, 0, stream>>>(qtA, S, (float*)d_out);
}

// Round 4
// 65.974 us; speedup vs baseline: 2.0725x; 1.0766x over previous
//
#include <hip/hip_runtime.h>
#include <hip/hip_bf16.h>

// EPN layer: B=8, N=256, F=32, E_DIM=8, HID=32, IN_DIM=74, T=3
// Per t:  P[n] = [h,q]@W1[0:33]+b1,  Q[n] = [h,q]@W1[33:66]
//   x1(dir0,i,j) = relu(P_i + Q_j + e_ij@W1e) ; dir1 swaps P/Q roles.
//   elec = relu(x1@W2 + b2)@W3 ; S_dir[i] = sum_j mn_ij*elec ;
//   q_next = q + 0.5*(S0 - S1).   (b3 cancels in the difference.)
// Phase A (layer 1) runs TRANSPOSED: x1^T = mfma(A=[W1e;I] frags, B=input rows)
//   with C = P_i[k] per-row. Input rows staged in LDS as [e(8)|J(32)] bf16;
//   identity-fold adds Q_j. Lane then holds 4 k for one j -> pure register
//   shuffle-exchange into phase-B A-frags (k order comes out standard).
// Phase B (layer 2) = round-2/3 validated MFMA + fused b2/relu/W3/mn epilogue.
// NO __syncthreads in the hot path (all LDS traffic is wave-local).

typedef __attribute__((ext_vector_type(8))) short short8;
typedef __attribute__((ext_vector_type(4))) float f32x4;
union U4S8 { uint4 u; short8 s; };

#define F4(p) (*(const float4*)(p))

__device__ __forceinline__ unsigned pkbf2(float lo, float hi) {
    unsigned a = __bfloat16_as_ushort(__float2bfloat16(lo));
    unsigned b = __bfloat16_as_ushort(__float2bfloat16(hi));
    return a | (b << 16);
}

// P/Q (fp32 + bf16), q_t materialization, W2T + WA fragment prepack.
__global__ __launch_bounds__(256) void epn_pre(
    const float* __restrict__ h, const float* __restrict__ qprev,
    const float* __restrict__ S, int use_parts,
    const float* __restrict__ W1, const float* __restrict__ b1,
    const float* __restrict__ W2,
    float* __restrict__ P, float* __restrict__ Q,
    unsigned short* __restrict__ Pbf, unsigned short* __restrict__ Qbf,
    unsigned* __restrict__ W2T, uint4* __restrict__ WA,
    float* __restrict__ qt)
{
    int gid = blockIdx.x * 256 + threadIdx.x;
    if (gid < 512) {
        // W2^T bf16-pair pack (validated round 2)
        int n = gid >> 4, kp = gid & 15;
        W2T[gid] = pkbf2(W2[(2*kp)*32 + n], W2[(2*kp+1)*32 + n]);
    } else if (gid < 640) {
        // Layer-1 A-frags (transposed): WA[kt*64+lane] : A[m=l15][d=sl*8+p]
        //   = W_comb[d][kt*16+l15];  W_comb = [W1e(8x32); I(32x32)]
        int g2 = gid - 512;
        int kt = g2 >> 6, lane = g2 & 63;
        int l15 = lane & 15, sl = lane >> 4;
        float v[8];
        #pragma unroll
        for (int p = 0; p < 8; ++p) {
            int d = sl*8 + p;
            v[p] = (d < 8) ? W1[(66+d)*32 + kt*16 + l15]
                           : ((kt*16 + l15 == d - 8) ? 1.0f : 0.0f);
        }
        WA[g2] = make_uint4(pkbf2(v[0],v[1]), pkbf2(v[2],v[3]),
                            pkbf2(v[4],v[5]), pkbf2(v[6],v[7]));
    }
    int node = gid >> 5;
    int k    = gid & 31;
    float qv = qprev[node];
    if (use_parts) qv += 0.5f * (S[node] - S[2048 + node]);
    if (k == 0) qt[node] = qv;
    const float* hn = h + node * 32;
    float p  = b1[k] + qv * W1[32*32 + k];
    float qq =         qv * W1[65*32 + k];
    #pragma unroll
    for (int f = 0; f < 32; ++f) {
        float hv = hn[f];
        p  += hv * W1[f*32 + k];
        qq += hv * W1[(33+f)*32 + k];
    }
    P[gid] = p;   Q[gid] = qq;
    Pbf[gid] = __bfloat16_as_ushort(__float2bfloat16(p));
    Qbf[gid] = __bfloat16_as_ushort(__float2bfloat16(qq));
}

// One block per (b,i,dir). Sout[dir*2048 + bi] = sum_j mn*elec.
__global__ __launch_bounds__(256, 4) void epn_main(
    const float* __restrict__ e, const float* __restrict__ mask,
    const float* __restrict__ P, const float* __restrict__ Q,
    const uint4* __restrict__ Pbf4, const uint4* __restrict__ Qbf4,
    const uint4* __restrict__ WA, const uint4* __restrict__ W2T4,
    const float* __restrict__ b2, const float* __restrict__ W3,
    float* __restrict__ Sout)
{
    __shared__ uint4 rows[256*6];   // [j][ e(16B) | J(64B) | pad(16B) ] = 24KB
    __shared__ float red[4];

    const int bid  = blockIdx.x;
    const int dir  = bid & 1;
    const int bi   = bid >> 1;        // b*256 + i
    const int b    = bi >> 8;
    const int tid  = threadIdx.x;
    const int j    = tid;
    const int lane = tid & 63, w = tid >> 6;
    const int l15  = lane & 15, sl = lane >> 4;

    // ---- stage row j = [e_ij(8 bf16) | J_j(32 bf16)] (wave-local use only) ----
    const float* ejp = e + ((size_t)bi * 256 + j) * 8;
    float4 e0 = F4(ejp), e1 = F4(ejp + 4);
    float mx = fmaxf(fmaxf(fmaxf(e0.x,e0.y),fmaxf(e0.z,e0.w)),
                     fmaxf(fmaxf(e1.x,e1.y),fmaxf(e1.z,e1.w)));
    float nearf = (fminf(fmaxf(mx, 1e-8f), 1e5f) != 1e-8f) ? 1.0f : 0.0f;
    float mn = mask[bi] * mask[b*256 + j] * nearf;   // 0.5 applied at combine
    rows[j*6] = make_uint4(pkbf2(e0.x,e0.y), pkbf2(e0.z,e0.w),
                           pkbf2(e1.x,e1.y), pkbf2(e1.z,e1.w));
    const uint4* Jsrc = dir ? Pbf4 : Qbf4;
    #pragma unroll
    for (int c = 0; c < 4; ++c)
        rows[j*6 + 1 + c] = Jsrc[(b*256 + j)*4 + c];

    // ---- hoisted fragments ----
    U4S8 wa00, wa01, wa1;
    wa00.u = WA[lane];        // kt=0, K-chunk 0
    wa01.u = WA[64 + lane];   // kt=1, K-chunk 0
    wa1.u  = make_uint4(0u,0u,0u,0u);   // kt=1, K-chunk 1 (I rows for Qj[24:32])
    if (sl == 0 && l15 >= 8) {
        int p = l15 - 8;
        unsigned v = 0x3F80u << ((p & 1) * 16);
        wa1.u.x = ((p>>1)==0) ? v : 0u;
        wa1.u.y = ((p>>1)==1) ? v : 0u;
        wa1.u.z = ((p>>1)==2) ? v : 0u;
        wa1.u.w = ((p>>1)==3) ? v : 0u;
    }
    const float* Csrc = dir ? Q : P;                   // dir0: P_i, dir1: Q_i
    f32x4 ck0 = *(const f32x4*)(Csrc + bi*32 + sl*4);        // P_i[sl*4+r]
    f32x4 ck1 = *(const f32x4*)(Csrc + bi*32 + 16 + sl*4);   // P_i[16+sl*4+r]
    U4S8 bu0, bu1;
    bu0.u = W2T4[l15*4 + sl];
    bu1.u = W2T4[(l15+16)*4 + sl];
    float b2v0 = b2[l15], b2v1 = b2[l15+16];
    float w3v0 = W3[l15], w3v1 = W3[l15+16];
    const int srcA = ((sl & 1) << 5) + l15;   // exchange source lanes
    const int srcB = srcA + 16;
    const bool ktHi = (sl >= 2);

    float tot = 0.f;
    #pragma unroll
    for (int rt = 0; rt < 4; ++rt) {
        // B-frags: input rows jb+l15 (wave-local LDS, no barrier needed)
        const int rowb = (w*64 + rt*16 + l15) * 6;
        U4S8 bc0, bc1;
        bc0.u = rows[rowb + sl];     // elems d = sl*8..sl*8+7 of [e|J]
        bc1.u = rows[rowb + 4];      // elems 32..39 (= Qj[24:32]); A zeros cover sl>0
        // layer-1: x1^T tiles, C = P_i rows
        f32x4 dk0 = __builtin_amdgcn_mfma_f32_16x16x32_bf16(wa00.s, bc0.s, ck0, 0,0,0);
        f32x4 dk1 = __builtin_amdgcn_mfma_f32_16x16x32_bf16(wa01.s, bc0.s, ck1, 0,0,0);
        dk1 = __builtin_amdgcn_mfma_f32_16x16x32_bf16(wa1.s, bc1.s, dk1, 0,0,0);
        // relu + bf16 pack: lane holds k = kt*16+sl*4+{0..3} for j = jb+l15
        unsigned pk00 = pkbf2(fmaxf(dk0[0],0.f), fmaxf(dk0[1],0.f));
        unsigned pk01 = pkbf2(fmaxf(dk0[2],0.f), fmaxf(dk0[3],0.f));
        unsigned pk10 = pkbf2(fmaxf(dk1[0],0.f), fmaxf(dk1[1],0.f));
        unsigned pk11 = pkbf2(fmaxf(dk1[2],0.f), fmaxf(dk1[3],0.f));
        // register exchange -> phase-B A-frag (k order = sl*8+p, standard)
        unsigned sA0l = __shfl(pk00, srcA), sA0h = __shfl(pk10, srcA);
        unsigned sA1l = __shfl(pk01, srcA), sA1h = __shfl(pk11, srcA);
        unsigned sB0l = __shfl(pk00, srcB), sB0h = __shfl(pk10, srcB);
        unsigned sB1l = __shfl(pk01, srcB), sB1h = __shfl(pk11, srcB);
        U4S8 a;
        a.u.x = ktHi ? sA0h : sA0l;
        a.u.y = ktHi ? sA1h : sA1l;
        a.u.z = ktHi ? sB0h : sB0l;
        a.u.w = ktHi ? sB1h : sB1l;
        // layer-2 MFMA + fused epilogue (validated round 2/3)
        f32x4 z = {0.f,0.f,0.f,0.f};
        f32x4 d0 = __builtin_amdgcn_mfma_f32_16x16x32_bf16(a.s, bu0.s, z, 0,0,0);
        f32x4 d1 = __builtin_amdgcn_mfma_f32_16x16x32_bf16(a.s, bu1.s, z, 0,0,0);
        const int jb = rt*16 + sl*4;
        float m0 = __shfl(mn, jb+0), m1 = __shfl(mn, jb+1);
        float m2 = __shfl(mn, jb+2), m3 = __shfl(mn, jb+3);
        float p0 = fmaxf(d0[0]+b2v0,0.f)*w3v0 + fmaxf(d1[0]+b2v1,0.f)*w3v1;
        float p1 = fmaxf(d0[1]+b2v0,0.f)*w3v0 + fmaxf(d1[1]+b2v1,0.f)*w3v1;
        float p2 = fmaxf(d0[2]+b2v0,0.f)*w3v0 + fmaxf(d1[2]+b2v1,0.f)*w3v1;
        float p3 = fmaxf(d0[3]+b2v0,0.f)*w3v0 + fmaxf(d1[3]+b2v1,0.f)*w3v1;
        tot += m0*p0 + m1*p1 + m2*p2 + m3*p3;
    }
    #pragma unroll
    for (int off = 32; off > 0; off >>= 1) tot += __shfl_down(tot, off);
    if (lane == 0) red[w] = tot;
    __syncthreads();
    if (tid == 0) Sout[dir*2048 + bi] = red[0] + red[1] + red[2] + red[3];
}

__global__ __launch_bounds__(256) void epn_fin(
    const float* __restrict__ qt, const float* __restrict__ S,
    float* __restrict__ out)
{
    int n = blockIdx.x * 256 + threadIdx.x;
    out[n] = qt[n] + 0.5f * (S[n] - S[2048 + n]);
}

extern "C" void kernel_launch(void* const* d_in, const int* in_sizes, int n_in,
                              void* d_out, int out_size, void* d_ws, size_t ws_size,
                              hipStream_t stream) {
    (void)in_sizes; (void)n_in; (void)out_size; (void)ws_size;
    const float* h    = (const float*)d_in[0];
    const float* e    = (const float*)d_in[1];
    const float* q    = (const float*)d_in[2];
    const float* mask = (const float*)d_in[3];
    const float* W1   = (const float*)d_in[4];
    const float* b1   = (const float*)d_in[5];
    const float* W2   = (const float*)d_in[6];
    const float* b2   = (const float*)d_in[7];
    const float* W3   = (const float*)d_in[8];

    float* wsf = (float*)d_ws;
    float* P   = wsf;                                   // [2048][32]
    float* Qm  = wsf + 65536;                           // [2048][32]
    unsigned short* Pbf = (unsigned short*)(wsf + 131072);  // 128KB
    unsigned short* Qbf = (unsigned short*)(wsf + 163840);  // 128KB
    float* qtA = wsf + 196608;                          // 2048
    float* qtB = wsf + 198656;                          // 2048
    float* S   = wsf + 200704;                          // [2][2048]
    unsigned* W2T = (unsigned*)(wsf + 204800);          // 512 u32
    uint4*    WA  = (uint4*)(wsf + 205312);             // 128 uint4

    for (int t = 0; t < 3; ++t) {
        const float* qsrc = (t == 0) ? q : (t == 1 ? qtA : qtB);
        float* qt_out     = (t == 1) ? qtB : qtA;
        epn_pre<<<256, 256, 0, stream>>>(h, qsrc, S, (t > 0) ? 1 : 0,
                                         W1 + t*74*32, b1 + t*32, W2 + t*32*32,
                                         P, Qm, Pbf, Qbf, W2T, WA, qt_out);
        epn_main<<<4096, 256, 0, stream>>>(e, mask, P, Qm,
                                           (const uint4*)Pbf, (const uint4*)Qbf,
                                           WA, (const uint4*)W2T,
                                           b2 + t*32, W3 + t*32, S);
    }
    epn_fin<<<8, 256, 0, stream>>>(qtA, S, (float*)d_out);
}

// Round 5
// 58.096 us; speedup vs baseline: 2.3535x; 1.1356x over previous
//
#include <hip/hip_runtime.h>
#include <hip/hip_bf16.h>

// EPN layer: B=8, N=256, F=32, E_DIM=8, HID=32, IN_DIM=74, T=3
// P_t[n] = baseP_t[n] + q_t[n]*W1_t[32,:]   (baseP = h@W1[0:32] + b1)
// Q_t[n] = baseQ_t[n] + q_t[n]*W1_t[65,:]   (baseQ = h@W1[33:65])
// x1(dir0) = relu(P_i + Q_j + e@W1e); dir1 swaps roles. elec = relu(x1@W2+b2)@W3.
// q_{t+1}[i] = q_t[i] + 0.5*sum_j mn_ij*(elec0 - elec1).  (b3 cancels.)
// 4 launches total: 1 pre (q-independent bases+frags for all t) + 3 mains.
// Main: transposed layer-1 MFMA (validated r4): x1^T = mfma(A=[W1e;I;qrow], B=rows)
//   rows = [e(8) | baseQ(32) | baseP(32)] bf16 in SoA LDS; q_j enters as K-chunk2
//   (B from register shfl), q_i enters via fp32 C. Register shuffle-exchange
//   into layer-2 A-frags (validated r4). Both dirs in one block; no barriers
//   in the hot path (LDS wave-local); block writes q_dst[i] directly.

typedef __attribute__((ext_vector_type(8))) short short8;
typedef __attribute__((ext_vector_type(4))) float f32x4;
union U4S8 { uint4 u; short8 s; };
#define F4(p) (*(const float4*)(p))

__device__ __forceinline__ unsigned pkbf2(float lo, float hi) {
    unsigned a = __bfloat16_as_ushort(__float2bfloat16(lo));
    unsigned b = __bfloat16_as_ushort(__float2bfloat16(hi));
    return a | (b << 16);
}
__device__ __forceinline__ float bf2f(unsigned short u) {
    return __uint_as_float(((unsigned)u) << 16);
}

// ---- pre: bases for all 3 t + W2T/WA fragment packs (q-independent) ----
__global__ __launch_bounds__(256) void epn_pre(
    const float* __restrict__ h, const float* __restrict__ W1,
    const float* __restrict__ b1, const float* __restrict__ W2,
    unsigned short* __restrict__ basePbf, unsigned short* __restrict__ baseQbf,
    unsigned* __restrict__ W2T, uint4* __restrict__ WA)
{
    const int t  = blockIdx.x >> 8;
    const int lg = (blockIdx.x & 255) * 256 + threadIdx.x;  // 0..65535
    const float* W1t = W1 + t*74*32;
    if (lg < 512) {
        // W2^T bf16-pair pack (validated r2)
        int n = lg >> 4, kp = lg & 15;
        const float* W2t = W2 + t*1024;
        W2T[t*512 + lg] = pkbf2(W2t[(2*kp)*32 + n], W2t[(2*kp+1)*32 + n]);
    } else if (lg < 640) {
        // layer-1 A frags, K-chunk 0 (d=0..31): [W1e ; I] (validated r4)
        int g2 = lg - 512;
        int kt = g2 >> 6, lane = g2 & 63;
        int l15 = lane & 15, sl = lane >> 4;
        float v[8];
        #pragma unroll
        for (int p = 0; p < 8; ++p) {
            int d = sl*8 + p;
            v[p] = (d < 8) ? W1t[(66+d)*32 + kt*16 + l15]
                           : ((kt*16 + l15 == d - 8) ? 1.0f : 0.0f);
        }
        WA[t*128 + g2] = make_uint4(pkbf2(v[0],v[1]), pkbf2(v[2],v[3]),
                                    pkbf2(v[4],v[5]), pkbf2(v[6],v[7]));
    }
    const int node = lg >> 5, k = lg & 31;
    const float* hn = h + node*32;
    float p = b1[t*32 + k], qq = 0.f;
    #pragma unroll
    for (int f = 0; f < 32; ++f) {
        float hv = hn[f];
        p  += hv * W1t[f*32 + k];
        qq += hv * W1t[(33+f)*32 + k];
    }
    basePbf[t*65536 + lg] = __bfloat16_as_ushort(__float2bfloat16(p));
    baseQbf[t*65536 + lg] = __bfloat16_as_ushort(__float2bfloat16(qq));
}

// ---- main: one block per (b,i), both dirs; writes q_dst[bi] ----
__global__ __launch_bounds__(256, 4) void epn_main(
    const float* __restrict__ e, const float* __restrict__ mask,
    const uint4* __restrict__ bP4, const uint4* __restrict__ bQ4,
    const float* __restrict__ qrowP, const float* __restrict__ qrowQ,
    const uint4* __restrict__ W2T4, const uint4* __restrict__ WA,
    const float* __restrict__ b2, const float* __restrict__ W3,
    const float* __restrict__ q_src, float* __restrict__ q_dst)
{
    __shared__ uint4 sx[9][256];   // SoA: slot0=e, 1-4=baseQ, 5-8=baseP (36.9KB)
    __shared__ float red[4];

    const int bi = blockIdx.x, b = bi >> 8;
    const int tid = threadIdx.x, j = tid;
    const int lane = tid & 63, w = tid >> 6;
    const int l15 = lane & 15, sl = lane >> 4;

    // ---------- staging (all wave-local consumption; no barrier) ----------
    float qj = q_src[b*256 + j];
    unsigned qpk = __bfloat16_as_ushort(__float2bfloat16(qj));
    const float* ejp = e + ((size_t)bi*256 + j)*8;
    float4 e0 = F4(ejp), e1 = F4(ejp + 4);
    float mx = fmaxf(fmaxf(fmaxf(e0.x,e0.y),fmaxf(e0.z,e0.w)),
                     fmaxf(fmaxf(e1.x,e1.y),fmaxf(e1.z,e1.w)));
    float nearf = (fminf(fmaxf(mx, 1e-8f), 1e5f) != 1e-8f) ? 1.f : 0.f;
    float mn = mask[bi] * mask[b*256 + j] * nearf;   // 0.5 applied at the end
    sx[0][j] = make_uint4(pkbf2(e0.x,e0.y), pkbf2(e0.z,e0.w),
                          pkbf2(e1.x,e1.y), pkbf2(e1.z,e1.w));
    {
        const uint4* bq = bQ4 + (size_t)(b*256 + j)*4;
        const uint4* bp = bP4 + (size_t)(b*256 + j)*4;
        sx[1][j]=bq[0]; sx[2][j]=bq[1]; sx[3][j]=bq[2]; sx[4][j]=bq[3];
        sx[5][j]=bp[0]; sx[6][j]=bp[1]; sx[7][j]=bp[2]; sx[8][j]=bp[3];
    }

    // ---------- hoisted fragments ----------
    U4S8 wa00, wa01, wa1;
    wa00.u = WA[lane];        // kt0, chunk0
    wa01.u = WA[64 + lane];   // kt1, chunk0
    wa1.u  = make_uint4(0u,0u,0u,0u);   // kt1, chunk1 (I rows for J[24:32])
    if (sl == 0 && l15 >= 8) {
        int p = l15 - 8;
        unsigned v = 0x3F80u << ((p & 1) * 16);
        wa1.u.x = ((p>>1)==0)?v:0u;  wa1.u.y = ((p>>1)==1)?v:0u;
        wa1.u.z = ((p>>1)==2)?v:0u;  wa1.u.w = ((p>>1)==3)?v:0u;
    }
    // chunk2 A scalars: q-row of W1 (j-side q contribution), per dir & kt
    unsigned aqQ0 = 0, aqQ1 = 0, aqP0 = 0, aqP1 = 0;
    if (sl == 0) {
        aqQ0 = __bfloat16_as_ushort(__float2bfloat16(qrowQ[l15]));
        aqQ1 = __bfloat16_as_ushort(__float2bfloat16(qrowQ[16 + l15]));
        aqP0 = __bfloat16_as_ushort(__float2bfloat16(qrowP[l15]));
        aqP1 = __bfloat16_as_ushort(__float2bfloat16(qrowP[16 + l15]));
    }
    // C vectors: dir0 C=P_i, dir1 C=Q_i (fp32: bf16 base + q_i * qrow)
    float qi = q_src[bi];
    const unsigned short* bPi = (const unsigned short*)bP4 + (size_t)bi*32;
    const unsigned short* bQi = (const unsigned short*)bQ4 + (size_t)bi*32;
    f32x4 ckP0, ckP1, ckQ0, ckQ1;
    #pragma unroll
    for (int r = 0; r < 4; ++r) {
        int k0 = sl*4 + r, k1 = 16 + sl*4 + r;
        ckP0[r] = bf2f(bPi[k0]) + qi * qrowP[k0];
        ckP1[r] = bf2f(bPi[k1]) + qi * qrowP[k1];
        ckQ0[r] = bf2f(bQi[k0]) + qi * qrowQ[k0];
        ckQ1[r] = bf2f(bQi[k1]) + qi * qrowQ[k1];
    }
    U4S8 bu0, bu1;
    bu0.u = W2T4[l15*4 + sl];
    bu1.u = W2T4[(l15 + 16)*4 + sl];
    float b2v0 = b2[l15], b2v1 = b2[l15+16];
    float w3v0 = W3[l15], w3v1 = W3[l15+16];
    const int srcA = ((sl & 1) << 5) + l15, srcB = srcA + 16;
    const bool ktHi = (sl >= 2);
    const int slot0_d0 = (sl == 0) ? 0 : sl;        // [e|baseQ] chunk0
    const int slot0_d1 = (sl == 0) ? 0 : 4 + sl;    // [e|baseP] chunk0

    float tot = 0.f;
    #pragma unroll
    for (int rt = 0; rt < 4; ++rt) {
        const int rl  = rt*16 + l15;
        const int row = w*64 + rl;
        unsigned qr = __shfl(qpk, rl);
        U4S8 bc2; bc2.u = make_uint4((sl == 0) ? (qr & 0xFFFFu) : 0u, 0u, 0u, 0u);
        float pA[4], pB[4];
        #pragma unroll
        for (int dir = 0; dir < 2; ++dir) {
            U4S8 bc0, bc1, aq0, aq1;
            bc0.u = sx[dir ? slot0_d1 : slot0_d0][row];
            bc1.u = sx[dir ? 8 : 4][row];
            aq0.u = make_uint4(dir ? aqP0 : aqQ0, 0u, 0u, 0u);
            aq1.u = make_uint4(dir ? aqP1 : aqQ1, 0u, 0u, 0u);
            f32x4 c0 = dir ? ckQ0 : ckP0;
            f32x4 c1 = dir ? ckQ1 : ckP1;
            // layer-1 (transposed): x1^T, K-chunks {0,2} for kt0, {0,1,2} for kt1
            f32x4 dk0 = __builtin_amdgcn_mfma_f32_16x16x32_bf16(wa00.s, bc0.s, c0, 0,0,0);
            dk0 = __builtin_amdgcn_mfma_f32_16x16x32_bf16(aq0.s, bc2.s, dk0, 0,0,0);
            f32x4 dk1 = __builtin_amdgcn_mfma_f32_16x16x32_bf16(wa01.s, bc0.s, c1, 0,0,0);
            dk1 = __builtin_amdgcn_mfma_f32_16x16x32_bf16(wa1.s,  bc1.s, dk1, 0,0,0);
            dk1 = __builtin_amdgcn_mfma_f32_16x16x32_bf16(aq1.s,  bc2.s, dk1, 0,0,0);
            // relu + pack + register exchange -> layer-2 A-frag (validated r4)
            unsigned pk00 = pkbf2(fmaxf(dk0[0],0.f), fmaxf(dk0[1],0.f));
            unsigned pk01 = pkbf2(fmaxf(dk0[2],0.f), fmaxf(dk0[3],0.f));
            unsigned pk10 = pkbf2(fmaxf(dk1[0],0.f), fmaxf(dk1[1],0.f));
            unsigned pk11 = pkbf2(fmaxf(dk1[2],0.f), fmaxf(dk1[3],0.f));
            unsigned sA0l = __shfl(pk00, srcA), sA0h = __shfl(pk10, srcA);
            unsigned sA1l = __shfl(pk01, srcA), sA1h = __shfl(pk11, srcA);
            unsigned sB0l = __shfl(pk00, srcB), sB0h = __shfl(pk10, srcB);
            unsigned sB1l = __shfl(pk01, srcB), sB1h = __shfl(pk11, srcB);
            U4S8 a;
            a.u.x = ktHi ? sA0h : sA0l;
            a.u.y = ktHi ? sA1h : sA1l;
            a.u.z = ktHi ? sB0h : sB0l;
            a.u.w = ktHi ? sB1h : sB1l;
            // layer-2 + fused b2/relu/W3 (validated r2)
            f32x4 z = {0.f, 0.f, 0.f, 0.f};
            f32x4 d0 = __builtin_amdgcn_mfma_f32_16x16x32_bf16(a.s, bu0.s, z, 0,0,0);
            f32x4 d1 = __builtin_amdgcn_mfma_f32_16x16x32_bf16(a.s, bu1.s, z, 0,0,0);
            float* pp = dir ? pB : pA;
            pp[0] = fmaxf(d0[0]+b2v0,0.f)*w3v0 + fmaxf(d1[0]+b2v1,0.f)*w3v1;
            pp[1] = fmaxf(d0[1]+b2v0,0.f)*w3v0 + fmaxf(d1[1]+b2v1,0.f)*w3v1;
            pp[2] = fmaxf(d0[2]+b2v0,0.f)*w3v0 + fmaxf(d1[2]+b2v1,0.f)*w3v1;
            pp[3] = fmaxf(d0[3]+b2v0,0.f)*w3v0 + fmaxf(d1[3]+b2v1,0.f)*w3v1;
        }
        const int jb = rt*16 + sl*4;
        float m0 = __shfl(mn, jb+0), m1 = __shfl(mn, jb+1);
        float m2 = __shfl(mn, jb+2), m3 = __shfl(mn, jb+3);
        tot += m0*(pA[0]-pB[0]) + m1*(pA[1]-pB[1])
             + m2*(pA[2]-pB[2]) + m3*(pA[3]-pB[3]);
    }
    #pragma unroll
    for (int off = 32; off > 0; off >>= 1) tot += __shfl_down(tot, off);
    if (lane == 0) red[w] = tot;
    __syncthreads();
    if (tid == 0)
        q_dst[bi] = q_src[bi] + 0.5f * (red[0] + red[1] + red[2] + red[3]);
}

extern "C" void kernel_launch(void* const* d_in, const int* in_sizes, int n_in,
                              void* d_out, int out_size, void* d_ws, size_t ws_size,
                              hipStream_t stream) {
    (void)in_sizes; (void)n_in; (void)out_size; (void)ws_size;
    const float* h    = (const float*)d_in[0];
    const float* e    = (const float*)d_in[1];
    const float* q    = (const float*)d_in[2];
    const float* mask = (const float*)d_in[3];
    const float* W1   = (const float*)d_in[4];
    const float* b1   = (const float*)d_in[5];
    const float* W2   = (const float*)d_in[6];
    const float* b2   = (const float*)d_in[7];
    const float* W3   = (const float*)d_in[8];

    char* ws = (char*)d_ws;
    unsigned short* basePbf = (unsigned short*)ws;            // 3*65536 ush = 384KB
    unsigned short* baseQbf = (unsigned short*)(ws + 393216); // 384KB
    float*    qA  = (float*)(ws + 786432);                    // 8KB
    float*    qB  = (float*)(ws + 794624);                    // 8KB
    unsigned* W2T = (unsigned*)(ws + 802816);                 // 3*512 u32
    uint4*    WA  = (uint4*)(ws + 808960);                    // 3*128 uint4

    epn_pre<<<768, 256, 0, stream>>>(h, W1, b1, W2, basePbf, baseQbf, W2T, WA);

    const float* qsrc = q;
    for (int t = 0; t < 3; ++t) {
        float* qdst = (t == 2) ? (float*)d_out : (t == 0 ? qA : qB);
        epn_main<<<2048, 256, 0, stream>>>(
            e, mask,
            (const uint4*)(basePbf + t*65536), (const uint4*)(baseQbf + t*65536),
            W1 + t*74*32 + 32*32, W1 + t*74*32 + 65*32,
            (const uint4*)(W2T + t*512), WA + t*128,
            b2 + t*32, W3 + t*32, qsrc, qdst);
        qsrc = qdst;
    }
}